// Round 3
// baseline (1565.850 us; speedup 1.0000x reference)
//
#include <hip/hip_runtime.h>

#define B_ 2
#define S_ 2048
#define H_ 4096
#define NH_ 32
#define NKV_ 8
#define HD_ 128

typedef __bf16 bf16;
typedef __bf16 bf16x8 __attribute__((ext_vector_type(8)));
typedef __bf16 bf16x4 __attribute__((ext_vector_type(4)));
typedef float floatx4 __attribute__((ext_vector_type(4)));

static __device__ __forceinline__ floatx4 fzero4() {
    floatx4 v; v[0] = 0.f; v[1] = 0.f; v[2] = 0.f; v[3] = 0.f; return v;
}

// ---------------------------------------------------------------------------
// bf16-compute GEMM:  C[M][col0..col0+Nt) = A[M][K] * Bt[Nt][K]^T.
// TA = float (converted to bf16 during LDS staging) or bf16.
// TC = float or bf16.  128x128 tile, BK=64, 256 threads = 4 waves.
// ---------------------------------------------------------------------------
template <typename TA, typename TC>
__global__ __launch_bounds__(256) void gemm_bt(const TA* __restrict__ A,
                                               const bf16* __restrict__ Bt,
                                               TC* __restrict__ C,
                                               int M, int Nt, int K,
                                               int ldC, int col0) {
    __shared__ __align__(16) bf16 As[128][72];   // +8 pad (2-way = free, m136)
    __shared__ __align__(16) bf16 Bs[128][72];

    const int tid  = threadIdx.x;
    const int w    = tid >> 6;
    const int lane = tid & 63;
    const int quad = lane >> 4;
    const int l16  = lane & 15;
    const int wr   = (w >> 1) * 64;
    const int wc   = (w & 1) * 64;
    const int m0   = blockIdx.y * 128;
    const int n0   = blockIdx.x * 128;

    floatx4 acc[4][4];
#pragma unroll
    for (int i = 0; i < 4; i++)
#pragma unroll
        for (int j = 0; j < 4; j++) acc[i][j] = fzero4();

    for (int k0 = 0; k0 < K; k0 += 64) {
        __syncthreads();
        if constexpr (sizeof(TA) == 4) {
            // fp32 A: 128x64 tile = 2048 float4, 8 per thread, convert->bf16
#pragma unroll
            for (int i = 0; i < 8; i++) {
                int vec = tid + 256 * i;
                int row = vec >> 4;               // 16 float4 per 64-elem row
                int col = (vec & 15) << 2;
                float4 f = *(const float4*)(A + (size_t)(m0 + row) * K + k0 + col);
                bf16x4 h;
                h[0] = (bf16)f.x; h[1] = (bf16)f.y;
                h[2] = (bf16)f.z; h[3] = (bf16)f.w;
                *(bf16x4*)&As[row][col] = h;
            }
        } else {
#pragma unroll
            for (int i = 0; i < 4; i++) {
                int vec = tid + 256 * i;
                int row = vec >> 3;
                int col = (vec & 7) << 3;
                *(bf16x8*)&As[row][col] =
                    *(const bf16x8*)((const bf16*)A + (size_t)(m0 + row) * K + k0 + col);
            }
        }
#pragma unroll
        for (int i = 0; i < 4; i++) {
            int vec = tid + 256 * i;
            int row = vec >> 3;
            int col = (vec & 7) << 3;
            *(bf16x8*)&Bs[row][col] =
                *(const bf16x8*)(Bt + (size_t)(n0 + row) * K + k0 + col);
        }
        __syncthreads();
#pragma unroll
        for (int ks = 0; ks < 64; ks += 32) {
            bf16x8 af[4], bfg[4];
#pragma unroll
            for (int i = 0; i < 4; i++)
                af[i] = *(const bf16x8*)&As[wr + i * 16 + l16][ks + quad * 8];
#pragma unroll
            for (int j = 0; j < 4; j++)
                bfg[j] = *(const bf16x8*)&Bs[wc + j * 16 + l16][ks + quad * 8];
#pragma unroll
            for (int i = 0; i < 4; i++)
#pragma unroll
                for (int j = 0; j < 4; j++)
                    acc[i][j] = __builtin_amdgcn_mfma_f32_16x16x32_bf16(
                        af[i], bfg[j], acc[i][j], 0, 0, 0);
        }
    }

    // D layout: row = quad*4 + r, col = l16  (m89-verified)
#pragma unroll
    for (int i = 0; i < 4; i++) {
#pragma unroll
        for (int r = 0; r < 4; r++) {
            int row = m0 + wr + i * 16 + quad * 4 + r;
#pragma unroll
            for (int j = 0; j < 4; j++) {
                int col = col0 + n0 + wc + j * 16 + l16;
                C[(size_t)row * ldC + col] = (TC)acc[i][j][r];
            }
        }
    }
}

// ---------------------------------------------------------------------------
// Batched strided transpose + dtype convert: out[z][c][r] = in_base(z)[r][c].
// ---------------------------------------------------------------------------
template <typename TI, typename TO>
__global__ void transpose_b(const TI* __restrict__ in, TO* __restrict__ out,
                            long long irs, long long ors,
                            int zdiv, long long zs1, long long zs2,
                            long long ozs) {
    __shared__ TI t[32][33];
    const int z = blockIdx.z;
    const TI* ip = in + (long long)(z / zdiv) * zs1 + (long long)(z % zdiv) * zs2;
    TO* op = out + (long long)z * ozs;
    const int r0 = blockIdx.y * 32, c0 = blockIdx.x * 32;
    const int tx = threadIdx.x, ty = threadIdx.y;   // block (32,8)
#pragma unroll
    for (int i = 0; i < 4; i++)
        t[ty + i * 8][tx] = ip[(long long)(r0 + ty + i * 8) * irs + c0 + tx];
    __syncthreads();
#pragma unroll
    for (int i = 0; i < 4; i++)
        op[(long long)(c0 + ty + i * 8) * ors + r0 + tx] = (TO)t[tx][ty + i * 8];
}

// ---------------------------------------------------------------------------
// RoPE on q in place.  q layout [b][s][h][d] bf16, cos/sin fp32 [b][s][d].
// ---------------------------------------------------------------------------
__global__ void rope_q(bf16* __restrict__ q, const float* __restrict__ cosb,
                       const float* __restrict__ sinb) {
    size_t idx = (size_t)blockIdx.x * 256 + threadIdx.x; // B*S*NH*64
    int dp = idx & 63;
    size_t t = idx >> 6;
    int h = (int)(t % NH_);
    size_t bs = t / NH_;                 // b*S + s
    size_t base = (bs * NH_ + h) * HD_;
    float x1 = (float)q[base + dp];
    float x2 = (float)q[base + dp + 64];
    float c1 = cosb[bs * HD_ + dp];
    float s1 = sinb[bs * HD_ + dp];
    float c2 = cosb[bs * HD_ + dp + 64];
    float s2 = sinb[bs * HD_ + dp + 64];
    q[base + dp]      = (bf16)(x1 * c1 - x2 * s1);
    q[base + dp + 64] = (bf16)(x2 * c2 + x1 * s2);
}

// ---------------------------------------------------------------------------
// RoPE + repack K:  kin [b][s][kv][d]  ->  kout [b][kv][s][d]   (bf16)
// ---------------------------------------------------------------------------
__global__ void repack_k_rope(const bf16* __restrict__ kin, bf16* __restrict__ kout,
                              const float* __restrict__ cosb,
                              const float* __restrict__ sinb) {
    size_t idx = (size_t)blockIdx.x * 256 + threadIdx.x; // B*S*NKV*64
    int dp = idx & 63;
    size_t t = idx >> 6;
    int kv = (int)(t % NKV_);
    size_t bs = t / NKV_;                // b*S + s
    int b = (int)(bs / S_);
    int s = (int)(bs % S_);
    size_t ibase = (bs * NKV_ + kv) * HD_;
    float x1 = (float)kin[ibase + dp];
    float x2 = (float)kin[ibase + dp + 64];
    float c1 = cosb[bs * HD_ + dp];
    float s1 = sinb[bs * HD_ + dp];
    float c2 = cosb[bs * HD_ + dp + 64];
    float s2 = sinb[bs * HD_ + dp + 64];
    size_t obase = (((size_t)b * NKV_ + kv) * S_ + s) * HD_;
    kout[obase + dp]      = (bf16)(x1 * c1 - x2 * s1);
    kout[obase + dp + 64] = (bf16)(x2 * c2 + x1 * s2);
}

// ---------------------------------------------------------------------------
// Causal flash attention, IN PLACE (O overwrites Q).  Safe: each block reads
// exactly its own (64 rows x head) Q-tile before any O write.
// Q/O [b][s][h][d], Kp [b][kv][s][d], Vt [b][kv][d][s], all bf16.
// Grid (S/64, B*NH), 256 threads (4 waves, 16 q-rows each).
// ---------------------------------------------------------------------------
__global__ __launch_bounds__(256) void flash_fwd(const bf16* Q,
                                                 const bf16* __restrict__ Kp,
                                                 const bf16* __restrict__ Vt,
                                                 bf16* O) {
    __shared__ __align__(16) bf16 Qs[64][136];
    __shared__ __align__(16) bf16 Ks[64][136];
    __shared__ __align__(16) bf16 Vs[128][72];
    __shared__ __align__(16) bf16 Ps[4][16][72];

    const float scale = 0.08838834764831845f;  // 1/sqrt(128)
    const int qb = blockIdx.x, bh = blockIdx.y;
    const int b = bh / NH_, h = bh % NH_, kv = h >> 2;  // NH/NKV = 4
    const int q0 = qb * 64;
    const int tid = threadIdx.x, w = tid >> 6, lane = tid & 63;
    const int quad = lane >> 4, l16 = lane & 15;

    const bf16* Qb = Q + ((size_t)b * S_ * NH_ + h) * HD_;
    const bf16* Kb = Kp + ((size_t)(b * NKV_ + kv)) * S_ * HD_;
    const bf16* Vb = Vt + ((size_t)(b * NKV_ + kv)) * (size_t)HD_ * S_;

    // stage Q tile (64 x 128)
#pragma unroll
    for (int i = 0; i < 4; i++) {
        int vec = tid + 256 * i;
        int row = vec >> 4, col = (vec & 15) << 3;
        *(bf16x8*)&Qs[row][col] =
            *(const bf16x8*)(Qb + (size_t)(q0 + row) * (NH_ * HD_) + col);
    }
    __syncthreads();
    bf16x8 qf[4];
#pragma unroll
    for (int ks = 0; ks < 4; ks++)
        qf[ks] = *(const bf16x8*)&Qs[w * 16 + l16][ks * 32 + quad * 8];

    floatx4 of[8];
#pragma unroll
    for (int n = 0; n < 8; n++) of[n] = fzero4();
    float mi[4], li[4];
#pragma unroll
    for (int r = 0; r < 4; r++) { mi[r] = -1e30f; li[r] = 0.f; }

    const int nT = qb + 1;
    for (int j = 0; j < nT; ++j) {
        __syncthreads();
        const int kbase = j * 64;
#pragma unroll
        for (int i = 0; i < 4; i++) {
            int vec = tid + 256 * i;
            {   // K tile 64 x 128
                int row = vec >> 4, col = (vec & 15) << 3;
                *(bf16x8*)&Ks[row][col] =
                    *(const bf16x8*)(Kb + (size_t)(kbase + row) * HD_ + col);
            }
            {   // V^T tile 128 x 64
                int row = vec >> 3, col = (vec & 7) << 3;
                *(bf16x8*)&Vs[row][col] =
                    *(const bf16x8*)(Vb + (size_t)row * S_ + kbase + col);
            }
        }
        __syncthreads();

        // scores: 16 q-rows x 64 keys per wave
        floatx4 sa[4];
#pragma unroll
        for (int n = 0; n < 4; n++) sa[n] = fzero4();
#pragma unroll
        for (int ks = 0; ks < 4; ks++) {
#pragma unroll
            for (int n = 0; n < 4; n++) {
                bf16x8 kf = *(const bf16x8*)&Ks[n * 16 + l16][ks * 32 + quad * 8];
                sa[n] = __builtin_amdgcn_mfma_f32_16x16x32_bf16(qf[ks], kf, sa[n], 0, 0, 0);
            }
        }

        const bool diag = (j == qb);
#pragma unroll
        for (int n = 0; n < 4; n++)
#pragma unroll
            for (int r = 0; r < 4; r++) {
                float s = sa[n][r] * scale;
                if (diag) {
                    int row = q0 + w * 16 + quad * 4 + r;
                    int col = kbase + n * 16 + l16;
                    if (col > row) s = -1e30f;
                }
                sa[n][r] = s;
            }

        // row max (16 lanes of a quad hold one row; butterfly over l16 bits)
        float al[4];
#pragma unroll
        for (int r = 0; r < 4; r++) {
            float m = sa[0][r];
#pragma unroll
            for (int n = 1; n < 4; n++) m = fmaxf(m, sa[n][r]);
            m = fmaxf(m, __shfl_xor(m, 1));
            m = fmaxf(m, __shfl_xor(m, 2));
            m = fmaxf(m, __shfl_xor(m, 4));
            m = fmaxf(m, __shfl_xor(m, 8));
            float mn = fmaxf(mi[r], m);
            al[r] = __expf(mi[r] - mn);
            mi[r] = mn;
        }

        float ls[4] = {0.f, 0.f, 0.f, 0.f};
#pragma unroll
        for (int n = 0; n < 4; n++)
#pragma unroll
            for (int r = 0; r < 4; r++) {
                float p = __expf(sa[n][r] - mi[r]);
                sa[n][r] = p;
                ls[r] += p;
            }
#pragma unroll
        for (int r = 0; r < 4; r++) {
            float s = ls[r];
            s += __shfl_xor(s, 1);
            s += __shfl_xor(s, 2);
            s += __shfl_xor(s, 4);
            s += __shfl_xor(s, 8);
            li[r] = li[r] * al[r] + s;
        }

        // P: D-layout -> LDS -> A-operand layout (uniform barrier)
#pragma unroll
        for (int n = 0; n < 4; n++)
#pragma unroll
            for (int r = 0; r < 4; r++)
                Ps[w][quad * 4 + r][n * 16 + l16] = (bf16)sa[n][r];
        __syncthreads();

        // rescale O
#pragma unroll
        for (int n = 0; n < 8; n++)
#pragma unroll
            for (int r = 0; r < 4; r++) of[n][r] *= al[r];

        // PV: P (16x64) x V (64x128)
#pragma unroll
        for (int ks = 0; ks < 2; ks++) {
            bf16x8 ap = *(const bf16x8*)&Ps[w][l16][ks * 32 + quad * 8];
#pragma unroll
            for (int n = 0; n < 8; n++) {
                bf16x8 vf = *(const bf16x8*)&Vs[n * 16 + l16][ks * 32 + quad * 8];
                of[n] = __builtin_amdgcn_mfma_f32_16x16x32_bf16(ap, vf, of[n], 0, 0, 0);
            }
        }
    }

    // epilogue: O /= l, write [b][s][h][d] (in place over Q)
#pragma unroll
    for (int r = 0; r < 4; r++) {
        float inv = 1.f / li[r];
        int srow = q0 + w * 16 + quad * 4 + r;
        size_t base = (((size_t)b * S_ + srow) * NH_ + h) * HD_;
        bf16* Ob = O + base;
#pragma unroll
        for (int n = 0; n < 8; n++)
            Ob[n * 16 + l16] = (bf16)(of[n][r] * inv);
    }
}

// ---------------------------------------------------------------------------
extern "C" void kernel_launch(void* const* d_in, const int* in_sizes, int n_in,
                              void* d_out, int out_size, void* d_ws, size_t ws_size,
                              hipStream_t stream) {
    // ALL reference tensors are float32 (setup_inputs uses jnp.float32).
    const float* hs   = (const float*)d_in[0];
    const float* cosb = (const float*)d_in[1];
    const float* sinb = (const float*)d_in[2];
    const float* wq   = (const float*)d_in[3];
    const float* wk   = (const float*)d_in[4];
    const float* wv   = (const float*)d_in[5];
    const float* wo   = (const float*)d_in[6];
    float* out = (float*)d_out;
    (void)in_sizes; (void)n_in; (void)out_size;

    // 72 MiB workspace (proven available: round-2 ran past this guard).
    const size_t NEED = (size_t)72 * 1024 * 1024;
    if (ws_size < NEED) return;

    char* ws = (char*)d_ws;
    size_t off = 0;
    auto alloc = [&](size_t elems) {
        bf16* p = (bf16*)(ws + off);
        off += elems * sizeof(bf16);
        return p;
    };
    bf16* wTs = alloc(1024ull * 4096);                    //  8 MiB bf16 strip
    bf16* q   = alloc((size_t)B_ * S_ * NH_ * HD_);       // 32 MiB (O in place)
    bf16* kr  = alloc((size_t)B_ * S_ * NKV_ * HD_);      //  8 MiB
    bf16* vr  = alloc((size_t)B_ * S_ * NKV_ * HD_);      //  8 MiB
    bf16* Kpk = alloc((size_t)B_ * NKV_ * S_ * HD_);      //  8 MiB
    bf16* Vtv = alloc((size_t)B_ * NKV_ * HD_ * S_);      //  8 MiB  => 72 MiB

    dim3 tb(32, 8, 1);

    // Q projection: 4 strips of 1024 cols through wTs (fp32 -> bf16^T)
    for (int s = 0; s < 4; s++) {
        transpose_b<float, bf16><<<dim3(32, 128, 1), tb, 0, stream>>>(
            wq + 1024 * s, wTs, 4096, 4096, 1, 0, 0, 0);
        gemm_bt<float, bf16><<<dim3(8, 32), 256, 0, stream>>>(
            hs, wTs, q, 4096, 1024, 4096, 4096, 1024 * s);
    }
    // K projection
    transpose_b<float, bf16><<<dim3(32, 128, 1), tb, 0, stream>>>(
        wk, wTs, 1024, 4096, 1, 0, 0, 0);
    gemm_bt<float, bf16><<<dim3(8, 32), 256, 0, stream>>>(
        hs, wTs, kr, 4096, 1024, 4096, 1024, 0);
    // V projection
    transpose_b<float, bf16><<<dim3(32, 128, 1), tb, 0, stream>>>(
        wv, wTs, 1024, 4096, 1, 0, 0, 0);
    gemm_bt<float, bf16><<<dim3(8, 32), 256, 0, stream>>>(
        hs, wTs, vr, 4096, 1024, 4096, 1024, 0);

    // rope + repacks
    rope_q<<<(B_ * S_ * NH_ * 64) / 256, 256, 0, stream>>>(q, cosb, sinb);
    repack_k_rope<<<(B_ * S_ * NKV_ * 64) / 256, 256, 0, stream>>>(kr, Kpk, cosb, sinb);
    // V: [b][s][kv][d] -> [b*kv][d][s]
    transpose_b<bf16, bf16><<<dim3(HD_ / 32, S_ / 32, B_ * NKV_), tb, 0, stream>>>(
        vr, Vtv, (long long)NKV_ * HD_, S_,
        NKV_, (long long)S_ * NKV_ * HD_, HD_, (long long)HD_ * S_);

    // attention (in place: O overwrites q)
    flash_fwd<<<dim3(S_ / 64, B_ * NH_), 256, 0, stream>>>(q, Kpk, Vtv, q);

    // output projection: 4 strips, fp32 output to d_out
    for (int s = 0; s < 4; s++) {
        transpose_b<float, bf16><<<dim3(32, 128, 1), tb, 0, stream>>>(
            wo + 1024 * s, wTs, 4096, 4096, 1, 0, 0, 0);
        gemm_bt<bf16, float><<<dim3(8, 32), 256, 0, stream>>>(
            q, wTs, out, 4096, 1024, 4096, 4096, 1024 * s);
    }
}